// Round 1
// baseline (485.758 us; speedup 1.0000x reference)
//
#include <hip/hip_runtime.h>
#include <math.h>

namespace {
constexpr int Bn = 8, Cn = 3, Hn = 512, Wn = 960;
constexpr int RS  = 3;                      // rows per strip (5 staged rows -> 57.6 KB LDS)
constexpr int TPB = 256;
constexpr int NSTRIP = (Hn + RS - 1) / RS;  // 171 (last strip has 2 rows)
constexpr float kC1 = 1e-4f;                // 0.01^2
constexpr float kC2 = 9e-4f;                // 0.03^2
constexpr float kEps2 = 1e-6f;              // 0.001^2 (charbonnier)
constexpr float kAlpha = 0.85f;
}

__global__ __launch_bounds__(TPB) void stereo_fused(
    const float* __restrict__ left, const float* __restrict__ right,
    const float* __restrict__ d_left, const float* __restrict__ d_right,
    const float* __restrict__ nonocc, float* __restrict__ acc)
{
    // warped-right rows [local_row 0..RS+1][c][x]; local_row = y - (y0-1)
    __shared__ float warpY[(RS + 2) * Cn * Wn];
    __shared__ float red[3][TPB / 64];

    const int strip = blockIdx.x;
    const int b = blockIdx.y;
    const int y0 = strip * RS;
    const int rows = min(RS, Hn - y0);
    const int tid = threadIdx.x;

    const float* leftB  = left   + (size_t)b * Cn * Hn * Wn;
    const float* rightB = right  + (size_t)b * Cn * Hn * Wn;
    const float* dL = d_left  + (size_t)b * Hn * Wn;
    const float* dR = d_right + (size_t)b * Hn * Wn;
    const float* no = nonocc  + (size_t)b * Hn * Wn;

    // ---- Phase 1: stage warped right (strip + halo rows) into LDS ----
    for (int i = tid; i < (RS + 2) * Wn; i += TPB) {
        int lrow = i / Wn;
        int x = i - lrow * Wn;
        int yy = y0 - 1 + lrow;
        if (yy < 0 || yy >= Hn) continue;   // garbage rows never read (count excludes them)
        float d = dL[yy * Wn + x];
        float xs = (float)x - d;
        float x0f = floorf(xs);
        float wx = xs - x0f;
        int x0i = (int)x0f;
        int x1i = min(max(x0i + 1, 0), Wn - 1);
        x0i = min(max(x0i, 0), Wn - 1);
        const float* rrow = rightB + yy * Wn;
        #pragma unroll
        for (int c = 0; c < Cn; ++c) {
            float v0 = rrow[c * Hn * Wn + x0i];
            float v1 = rrow[c * Hn * Wn + x1i];
            warpY[(lrow * Cn + c) * Wn + x] = (1.f - wx) * v0 + wx * v1;
        }
    }
    __syncthreads();

    // ---- Phase 2: per-pixel SSIM + L1 + LR, accumulate masked sums ----
    float p_sum = 0.f, v_sum = 0.f, l_sum = 0.f;
    for (int i = tid; i < rows * Wn; i += TPB) {
        int ry = i / Wn;
        int x = i - ry * Wn;
        int y = y0 + ry;

        float d = dL[y * Wn + x];
        float xs = (float)x - d;
        float gx = 2.f * xs / (float)(Wn - 1) - 1.f;
        float validb = (gx >= -1.f && gx <= 1.f) ? 1.f : 0.f;
        float vw = validb * no[y * Wn + x];

        int ylo = max(y - 1, 0), yhi = min(y + 1, Hn - 1);
        int xlo = max(x - 1, 0), xhi = min(x + 1, Wn - 1);
        float inv_cnt = 1.f / (float)((yhi - ylo + 1) * (xhi - xlo + 1));

        float s_sum = 0.f, l1_sum = 0.f;
        #pragma unroll
        for (int c = 0; c < Cn; ++c) {
            float Sx = 0.f, Sy = 0.f, Sxx = 0.f, Syy = 0.f, Sxy = 0.f;
            for (int yy = ylo; yy <= yhi; ++yy) {
                const float* lrowp = leftB + (c * Hn + yy) * Wn;
                const float* wrow  = &warpY[((yy - y0 + 1) * Cn + c) * Wn];
                for (int xx = xlo; xx <= xhi; ++xx) {
                    float lx = lrowp[xx];
                    float ly = wrow[xx];
                    Sx += lx; Sy += ly;
                    Sxx += lx * lx; Syy += ly * ly; Sxy += lx * ly;
                }
            }
            float mu_x = Sx * inv_cnt, mu_y = Sy * inv_cnt;
            float sig_x  = Sxx * inv_cnt - mu_x * mu_x;
            float sig_y  = Syy * inv_cnt - mu_y * mu_y;
            float sig_xy = Sxy * inv_cnt - mu_x * mu_y;
            float num = (2.f * mu_x * mu_y + kC1) * (2.f * sig_xy + kC2);
            float den = (mu_x * mu_x + mu_y * mu_y + kC1) * (sig_x + sig_y + kC2);
            float ssim = num / (den + 1e-12f);
            float sm = 0.5f * (1.f - ssim);
            s_sum += fminf(fmaxf(sm, 0.f), 1.f);

            float lx0 = leftB[(c * Hn + y) * Wn + x];
            float ly0 = warpY[((ry + 1) * Cn + c) * Wn + x];
            float df = lx0 - ly0;
            l1_sum += sqrtf(df * df + kEps2);
        }
        float photo = (kAlpha * s_sum + (1.f - kAlpha) * l1_sum) * (1.f / 3.f);

        // LR consistency: warp d_right with the same taps
        float x0f = floorf(xs);
        float wx = xs - x0f;
        int x0i = (int)x0f;
        int x1i = min(max(x0i + 1, 0), Wn - 1);
        x0i = min(max(x0i, 0), Wn - 1);
        float drw = (1.f - wx) * dR[y * Wn + x0i] + wx * dR[y * Wn + x1i];
        float dd = d - drw;
        float lr_v = sqrtf(dd * dd + kEps2);

        p_sum += photo * vw;
        v_sum += vw;            // valid_lr == valid*nonocc (same disparity -> same mask)
        l_sum += lr_v * vw;
    }

    // ---- Block reduction -> 3 global atomics ----
    #pragma unroll
    for (int off = 32; off > 0; off >>= 1) {
        p_sum += __shfl_down(p_sum, off);
        v_sum += __shfl_down(v_sum, off);
        l_sum += __shfl_down(l_sum, off);
    }
    int lane = tid & 63, wv = tid >> 6;
    if (lane == 0) { red[0][wv] = p_sum; red[1][wv] = v_sum; red[2][wv] = l_sum; }
    __syncthreads();
    if (tid == 0) {
        float P = 0.f, V = 0.f, L = 0.f;
        #pragma unroll
        for (int i = 0; i < TPB / 64; ++i) { P += red[0][i]; V += red[1][i]; L += red[2][i]; }
        atomicAdd(&acc[0], P);
        atomicAdd(&acc[1], V);
        atomicAdd(&acc[2], L);
    }
}

__global__ void stereo_finalize(const float* __restrict__ acc, float* __restrict__ out)
{
    float P = acc[0], V = acc[1], L = acc[2];
    float photo = P / (V + 1e-6f);
    float lr = L / (V + 1e-6f);
    out[0] = photo + 0.2f * lr;   // W_PHOTO=1, W_LR=0.2
    out[1] = photo;
    out[2] = lr;
    out[3] = V * (1.f / (float)(Bn * Hn * Wn));
}

extern "C" void kernel_launch(void* const* d_in, const int* in_sizes, int n_in,
                              void* d_out, int out_size, void* d_ws, size_t ws_size,
                              hipStream_t stream) {
    const float* left   = (const float*)d_in[0];
    const float* right  = (const float*)d_in[1];
    const float* dl     = (const float*)d_in[2];
    const float* dr     = (const float*)d_in[3];
    const float* nonocc = (const float*)d_in[4];
    float* acc = (float*)d_ws;
    float* out = (float*)d_out;

    hipMemsetAsync(acc, 0, 3 * sizeof(float), stream);
    dim3 grid(NSTRIP, Bn);
    stereo_fused<<<grid, TPB, 0, stream>>>(left, right, dl, dr, nonocc, acc);
    stereo_finalize<<<1, 1, 0, stream>>>(acc, out);
}

// Round 2
// 297.762 us; speedup vs baseline: 1.6314x; 1.6314x over previous
//
#include <hip/hip_runtime.h>
#include <math.h>

namespace {
constexpr int Bn = 8, Cn = 3, Hn = 512, Wn = 960;
constexpr int RS = 8;             // output rows per strip
constexpr int SR = RS + 2;        // staged rows (strip + 1-row halo each side)
constexpr int Wp = Wn + 2;        // LDS row padded with zero border cols
constexpr int TPB = Wn;           // 960 threads = 15 waves; thread x = column
constexpr int NSTRIP = Hn / RS;   // 64 (exact)
constexpr float kC1 = 1e-4f;      // 0.01^2
constexpr float kC2 = 9e-4f;      // 0.03^2
constexpr float kEps2 = 1e-6f;    // 0.001^2
}

__global__ __launch_bounds__(TPB) void stereo_fused(
    const float* __restrict__ left, const float* __restrict__ right,
    const float* __restrict__ d_left, const float* __restrict__ d_right,
    const float* __restrict__ nonocc, float* __restrict__ acc)
{
    __shared__ float sW[SR][Wp];          // warped right, one channel at a time
    __shared__ float red[3][TPB / 64];

    const int x = threadIdx.x;            // 0..959
    const int strip = blockIdx.x;
    const int b = blockIdx.y;
    const int y0 = strip * RS;

    const float* leftB  = left   + (size_t)b * Cn * Hn * Wn;
    const float* rightB = right  + (size_t)b * Cn * Hn * Wn;
    const float* dL = d_left  + (size_t)b * Hn * Wn;
    const float* dR = d_right + (size_t)b * Hn * Wn;
    const float* no = nonocc  + (size_t)b * Hn * Wn;

    // zero LDS border columns once (never overwritten by staging)
    if (x == 0) {
        #pragma unroll
        for (int r = 0; r < SR; ++r) { sW[r][0] = 0.f; sW[r][Wp - 1] = 0.f; }
    }

    // ---- pre-pass: warp coords per staged row; mask/LR terms per output row ----
    float xs_r[SR];
    #pragma unroll
    for (int r = 0; r < SR; ++r) {
        int y = y0 - 1 + r;
        int yc = min(max(y, 0), Hn - 1);
        float d = dL[yc * Wn + x];                       // always-valid address
        xs_r[r] = (float)x - d;                          // garbage rows masked later
    }

    float vw_r[RS];
    float p_sum = 0.f, v_sum = 0.f, l_sum = 0.f;
    #pragma unroll
    for (int k = 0; k < RS; ++k) {
        int y = y0 + k;
        float xs = xs_r[k + 1];
        float gx = 2.f * xs / (float)(Wn - 1) - 1.f;
        float vmask = (gx >= -1.f && gx <= 1.f) ? 1.f : 0.f;
        float vw = vmask * no[y * Wn + x];
        vw_r[k] = vw;
        v_sum += vw;
        // LR consistency: warp d_right with same taps
        float x0f = floorf(xs);
        float wx = xs - x0f;
        int xi = (int)x0f;
        int x0i = min(max(xi, 0), Wn - 1);
        int x1i = min(max(xi + 1, 0), Wn - 1);
        const float* drow = dR + y * Wn;
        float drw = (1.f - wx) * drow[x0i] + wx * drow[x1i];
        float dd = ((float)x - xs) - drw;
        l_sum += sqrtf(dd * dd + kEps2) * vw;
    }

    const float xm_l = (x > 0) ? 1.f : 0.f;        // horizontal pad masks for left
    const float xm_r = (x < Wn - 1) ? 1.f : 0.f;
    const int xl = max(x - 1, 0), xr = min(x + 1, Wn - 1);
    const float inv_cx = (x == 0 || x == Wn - 1) ? 0.5f : (1.f / 3.f);

    #pragma unroll
    for (int c = 0; c < Cn; ++c) {
        __syncthreads();                  // prior channel's reads done before overwrite
        // ---- stage warped right channel c (zeros for out-of-image rows) ----
        #pragma unroll
        for (int r = 0; r < SR; ++r) {
            int y = y0 - 1 + r;
            float wv = 0.f;
            if (y >= 0 && y < Hn) {       // wave-uniform branch
                float xs = xs_r[r];
                float x0f = floorf(xs);
                float wx = xs - x0f;
                int xi = (int)x0f;
                int x0i = min(max(xi, 0), Wn - 1);
                int x1i = min(max(xi + 1, 0), Wn - 1);
                const float* rrow = rightB + ((size_t)c * Hn + y) * Wn;
                wv = (1.f - wx) * rrow[x0i] + wx * rrow[x1i];
            }
            sW[r][x + 1] = wv;
        }
        __syncthreads();

        // ---- vertical ring over staged rows: 3 taps left + 3 taps warped each ----
        float lA[3][3], wA[3][3];
        #pragma unroll
        for (int r = 0; r < 2; ++r) {     // preload staged rows 0,1 into slots 0,1
            int y = y0 - 1 + r;
            int yc = min(max(y, 0), Hn - 1);
            float ym = (y >= 0 && y < Hn) ? 1.f : 0.f;
            const float* lrow = leftB + ((size_t)c * Hn + yc) * Wn;
            lA[r][0] = lrow[xl] * (ym * xm_l);
            lA[r][1] = lrow[x] * ym;
            lA[r][2] = lrow[xr] * (ym * xm_r);
            wA[r][0] = sW[r][x];
            wA[r][1] = sW[r][x + 1];
            wA[r][2] = sW[r][x + 2];
        }
        #pragma unroll
        for (int k = 0; k < RS; ++k) {
            const int rn = k + 2;         // new staged row
            const int sn = rn % 3;
            {
                int y = y0 - 1 + rn;
                int yc = min(max(y, 0), Hn - 1);
                float ym = (y >= 0 && y < Hn) ? 1.f : 0.f;
                const float* lrow = leftB + ((size_t)c * Hn + yc) * Wn;
                lA[sn][0] = lrow[xl] * (ym * xm_l);
                lA[sn][1] = lrow[x] * ym;
                lA[sn][2] = lrow[xr] * (ym * xm_r);
                wA[sn][0] = sW[rn][x];
                wA[sn][1] = sW[rn][x + 1];
                wA[sn][2] = sW[rn][x + 2];
            }
            float Sx = 0.f, Sy = 0.f, Sxx = 0.f, Syy = 0.f, Sxy = 0.f;
            #pragma unroll
            for (int s = 0; s < 3; ++s)
                #pragma unroll
                for (int j = 0; j < 3; ++j) {
                    float l = lA[s][j], w = wA[s][j];
                    Sx += l; Sy += w;
                    Sxx = fmaf(l, l, Sxx);
                    Syy = fmaf(w, w, Syy);
                    Sxy = fmaf(l, w, Sxy);
                }
            int y = y0 + k;
            float inv_cy = (y == 0 || y == Hn - 1) ? 0.5f : (1.f / 3.f);
            float inv = inv_cy * inv_cx;
            float mu_x = Sx * inv, mu_y = Sy * inv;
            float sig_x  = Sxx * inv - mu_x * mu_x;
            float sig_y  = Syy * inv - mu_y * mu_y;
            float sig_xy = Sxy * inv - mu_x * mu_y;
            float num = (2.f * mu_x * mu_y + kC1) * (2.f * sig_xy + kC2);
            float den = (mu_x * mu_x + mu_y * mu_y + kC1) * (sig_x + sig_y + kC2);
            float ssim = num / (den + 1e-12f);
            float sm = fminf(fmaxf(0.5f * (1.f - ssim), 0.f), 1.f);
            // L1 term from window centers (slot (k+1)%3, tap 1)
            float lc = lA[(k + 1) % 3][1], wc = wA[(k + 1) % 3][1];
            float df = lc - wc;
            float l1 = sqrtf(df * df + kEps2);
            // photo contribution: alpha/3 * ssim_part + (1-alpha)/3 * l1_part
            p_sum += (0.28333333333f * sm + 0.05f * l1) * vw_r[k];
        }
    }

    // ---- block reduction -> 3 global atomics ----
    #pragma unroll
    for (int off = 32; off > 0; off >>= 1) {
        p_sum += __shfl_down(p_sum, off);
        v_sum += __shfl_down(v_sum, off);
        l_sum += __shfl_down(l_sum, off);
    }
    int lane = x & 63, wv = x >> 6;
    if (lane == 0) { red[0][wv] = p_sum; red[1][wv] = v_sum; red[2][wv] = l_sum; }
    __syncthreads();
    if (x == 0) {
        float P = 0.f, V = 0.f, L = 0.f;
        #pragma unroll
        for (int i = 0; i < TPB / 64; ++i) { P += red[0][i]; V += red[1][i]; L += red[2][i]; }
        atomicAdd(&acc[0], P);
        atomicAdd(&acc[1], V);
        atomicAdd(&acc[2], L);
    }
}

__global__ void stereo_finalize(const float* __restrict__ acc, float* __restrict__ out)
{
    float P = acc[0], V = acc[1], L = acc[2];
    float photo = P / (V + 1e-6f);
    float lr = L / (V + 1e-6f);
    out[0] = photo + 0.2f * lr;   // W_PHOTO=1, W_LR=0.2
    out[1] = photo;
    out[2] = lr;
    out[3] = V * (1.f / (float)(Bn * Hn * Wn));
}

extern "C" void kernel_launch(void* const* d_in, const int* in_sizes, int n_in,
                              void* d_out, int out_size, void* d_ws, size_t ws_size,
                              hipStream_t stream) {
    const float* left   = (const float*)d_in[0];
    const float* right  = (const float*)d_in[1];
    const float* dl     = (const float*)d_in[2];
    const float* dr     = (const float*)d_in[3];
    const float* nonocc = (const float*)d_in[4];
    float* acc = (float*)d_ws;
    float* out = (float*)d_out;

    hipMemsetAsync(acc, 0, 3 * sizeof(float), stream);
    dim3 grid(NSTRIP, Bn);
    stereo_fused<<<grid, TPB, 0, stream>>>(left, right, dl, dr, nonocc, acc);
    stereo_finalize<<<1, 1, 0, stream>>>(acc, out);
}

// Round 3
// 294.963 us; speedup vs baseline: 1.6468x; 1.0095x over previous
//
#include <hip/hip_runtime.h>
#include <math.h>

namespace {
constexpr int Bn = 8, Cn = 3, Hn = 512, Wn = 960;
constexpr int RS = 8;             // output rows per strip
constexpr int SR = RS + 2;        // staged rows (strip + halo)
constexpr int Wp = Wn + 2;        // LDS row with zero border cols
constexpr int TPB = Wn;           // 960 threads = 15 waves; thread = column
constexpr int NSTRIP = Hn / RS;   // 64
constexpr int NBLK = NSTRIP * Bn; // 512 blocks total
constexpr float kC1 = 1e-4f;      // 0.01^2
constexpr float kC2 = 9e-4f;      // 0.03^2
constexpr float kEps2 = 1e-6f;    // 0.001^2
}

__global__ __launch_bounds__(TPB) void stereo_fused(
    const float* __restrict__ left, const float* __restrict__ right,
    const float* __restrict__ d_left, const float* __restrict__ d_right,
    const float* __restrict__ nonocc, float* __restrict__ acc,
    float* __restrict__ out)
{
    __shared__ float sW[SR][Wp];          // warped right, one channel at a time
    __shared__ float red[3][TPB / 64];

    const int x = threadIdx.x;            // 0..959
    const int strip = blockIdx.x;
    const int b = blockIdx.y;
    const int y0 = strip * RS;

    const float* leftB  = left   + (size_t)b * Cn * Hn * Wn;
    const float* rightB = right  + (size_t)b * Cn * Hn * Wn;
    const float* dL = d_left  + (size_t)b * Hn * Wn;
    const float* dR = d_right + (size_t)b * Hn * Wn;
    const float* no = nonocc  + (size_t)b * Hn * Wn;

    if (x == 0) {                         // zero LDS border columns (never overwritten)
        #pragma unroll
        for (int r = 0; r < SR; ++r) { sW[r][0] = 0.f; sW[r][Wp - 1] = 0.f; }
    }

    // ---- Phase A: per output row: valid weight, LR loss ----
    float vw_r[RS];
    float p_sum = 0.f, v_sum = 0.f, l_sum = 0.f;
    #pragma unroll
    for (int k = 0; k < RS; ++k) {
        int y = y0 + k;
        float d = dL[y * Wn + x];
        float xs = (float)x - d;
        float gx = 2.f * xs / (float)(Wn - 1) - 1.f;
        float vmask = (gx >= -1.f && gx <= 1.f) ? 1.f : 0.f;
        float vw = vmask * no[y * Wn + x];
        vw_r[k] = vw;
        v_sum += vw;
        float x0f = floorf(xs);
        float wx = xs - x0f;
        int xi = (int)x0f;
        int x0i = min(max(xi, 0), Wn - 1);
        int x1i = min(max(xi + 1, 0), Wn - 1);
        const float* drow = dR + y * Wn;
        float drw = (1.f - wx) * drow[x0i] + wx * drow[x1i];
        float dd = d - drw;
        l_sum += sqrtf(dd * dd + kEps2) * vw;
    }

    const float xm_l = (x > 0) ? 1.f : 0.f;
    const float xm_r = (x < Wn - 1) ? 1.f : 0.f;
    const int xl = max(x - 1, 0), xr = min(x + 1, Wn - 1);
    const float inv_cx = (x == 0 || x == Wn - 1) ? 0.5f : (1.f / 3.f);

    #pragma unroll
    for (int c = 0; c < Cn; ++c) {
        __syncthreads();                  // prior channel's reads done before overwrite
        // ---- stage warped right channel c (xs recomputed from dL: L1-hot) ----
        #pragma unroll
        for (int r = 0; r < SR; ++r) {
            int y = y0 - 1 + r;
            float wv = 0.f;
            if (y >= 0 && y < Hn) {       // wave-uniform
                float xs = (float)x - dL[y * Wn + x];
                float x0f = floorf(xs);
                float wx = xs - x0f;
                int xi = (int)x0f;
                int x0i = min(max(xi, 0), Wn - 1);
                int x1i = min(max(xi + 1, 0), Wn - 1);
                const float* rrow = rightB + ((size_t)c * Hn + y) * Wn;
                wv = (1.f - wx) * rrow[x0i] + wx * rrow[x1i];
            }
            sW[r][x + 1] = wv;
        }
        __syncthreads();

        // ---- vertical ring: 3 rows x 3 taps of left (global/L1) + warped (LDS) ----
        float lA[3][3], wA[3][3];
        #pragma unroll
        for (int r = 0; r < 2; ++r) {
            int y = y0 - 1 + r;
            int yc = min(max(y, 0), Hn - 1);
            float ym = (y >= 0 && y < Hn) ? 1.f : 0.f;
            const float* lrow = leftB + ((size_t)c * Hn + yc) * Wn;
            lA[r][0] = lrow[xl] * (ym * xm_l);
            lA[r][1] = lrow[x] * ym;
            lA[r][2] = lrow[xr] * (ym * xm_r);
            wA[r][0] = sW[r][x];
            wA[r][1] = sW[r][x + 1];
            wA[r][2] = sW[r][x + 2];
        }
        #pragma unroll
        for (int k = 0; k < RS; ++k) {
            const int rn = k + 2;
            const int sn = rn % 3;
            {
                int y = y0 - 1 + rn;
                int yc = min(max(y, 0), Hn - 1);
                float ym = (y >= 0 && y < Hn) ? 1.f : 0.f;
                const float* lrow = leftB + ((size_t)c * Hn + yc) * Wn;
                lA[sn][0] = lrow[xl] * (ym * xm_l);
                lA[sn][1] = lrow[x] * ym;
                lA[sn][2] = lrow[xr] * (ym * xm_r);
                wA[sn][0] = sW[rn][x];
                wA[sn][1] = sW[rn][x + 1];
                wA[sn][2] = sW[rn][x + 2];
            }
            float Sx = 0.f, Sy = 0.f, Sxx = 0.f, Syy = 0.f, Sxy = 0.f;
            #pragma unroll
            for (int s = 0; s < 3; ++s)
                #pragma unroll
                for (int j = 0; j < 3; ++j) {
                    float l = lA[s][j], w = wA[s][j];
                    Sx += l; Sy += w;
                    Sxx = fmaf(l, l, Sxx);
                    Syy = fmaf(w, w, Syy);
                    Sxy = fmaf(l, w, Sxy);
                }
            int y = y0 + k;
            float inv_cy = (y == 0 || y == Hn - 1) ? 0.5f : (1.f / 3.f);
            float inv = inv_cy * inv_cx;
            float mu_x = Sx * inv, mu_y = Sy * inv;
            float sig_x  = Sxx * inv - mu_x * mu_x;
            float sig_y  = Syy * inv - mu_y * mu_y;
            float sig_xy = Sxy * inv - mu_x * mu_y;
            float num = (2.f * mu_x * mu_y + kC1) * (2.f * sig_xy + kC2);
            float den = (mu_x * mu_x + mu_y * mu_y + kC1) * (sig_x + sig_y + kC2);
            float ssim = num / (den + 1e-12f);
            float sm = fminf(fmaxf(0.5f * (1.f - ssim), 0.f), 1.f);
            float lc = lA[(k + 1) % 3][1], wc = wA[(k + 1) % 3][1];
            float df = lc - wc;
            float l1 = sqrtf(df * df + kEps2);
            p_sum += (0.28333333333f * sm + 0.05f * l1) * vw_r[k];  // alpha/3, (1-alpha)/3
        }
    }

    // ---- block reduction -> 3 global atomics -> ticketed finalize ----
    #pragma unroll
    for (int off = 32; off > 0; off >>= 1) {
        p_sum += __shfl_down(p_sum, off);
        v_sum += __shfl_down(v_sum, off);
        l_sum += __shfl_down(l_sum, off);
    }
    int lane = x & 63, wv = x >> 6;
    if (lane == 0) { red[0][wv] = p_sum; red[1][wv] = v_sum; red[2][wv] = l_sum; }
    __syncthreads();
    if (x == 0) {
        float P = 0.f, V = 0.f, L = 0.f;
        #pragma unroll
        for (int i = 0; i < TPB / 64; ++i) { P += red[0][i]; V += red[1][i]; L += red[2][i]; }
        atomicAdd(&acc[0], P);
        atomicAdd(&acc[1], V);
        atomicAdd(&acc[2], L);
        __threadfence();
        unsigned prev = atomicAdd((unsigned*)&acc[3], 1u);
        if (prev == NBLK - 1) {           // last block finalizes
            float Pa = atomicAdd(&acc[0], 0.f);
            float Va = atomicAdd(&acc[1], 0.f);
            float La = atomicAdd(&acc[2], 0.f);
            float photo = Pa / (Va + 1e-6f);
            float lr = La / (Va + 1e-6f);
            out[0] = photo + 0.2f * lr;   // W_PHOTO=1, W_LR=0.2
            out[1] = photo;
            out[2] = lr;
            out[3] = Va * (1.f / (float)(Bn * Hn * Wn));
        }
    }
}

extern "C" void kernel_launch(void* const* d_in, const int* in_sizes, int n_in,
                              void* d_out, int out_size, void* d_ws, size_t ws_size,
                              hipStream_t stream) {
    const float* left   = (const float*)d_in[0];
    const float* right  = (const float*)d_in[1];
    const float* dl     = (const float*)d_in[2];
    const float* dr     = (const float*)d_in[3];
    const float* nonocc = (const float*)d_in[4];
    float* acc = (float*)d_ws;
    float* out = (float*)d_out;

    hipMemsetAsync(acc, 0, 4 * sizeof(float), stream);
    dim3 grid(NSTRIP, Bn);
    stereo_fused<<<grid, TPB, 0, stream>>>(left, right, dl, dr, nonocc, acc, out);
}